// Round 13
// baseline (162.416 us; speedup 1.0000x reference)
//
#include <hip/hip_runtime.h>
#include <stdint.h>

using i32x4  = __attribute__((ext_vector_type(4))) int;
using i32x16 = __attribute__((ext_vector_type(16))) int;

// ---------------- ws layout ----------------
#define WS_SCALED   2048
#define WS_SCALEF   2056
#define WS_FACT     4096
#define WS_XQ       (1u << 20)
#define WS_QW       ((1u << 20) + (32u << 20))

// ---------------- kernel 1: fused aquant (blocks 0..8191) + wabs partials (8192..8447) ----
__device__ inline int q8pack(float4 f, float as) {
    int a = (int)fminf(fmaxf(rintf(f.x * as), -128.0f), 127.0f);
    int b = (int)fminf(fmaxf(rintf(f.y * as), -128.0f), 127.0f);
    int c = (int)fminf(fmaxf(rintf(f.z * as), -128.0f), 127.0f);
    int d = (int)fminf(fmaxf(rintf(f.w * as), -128.0f), 127.0f);
    return (a & 0xff) | ((b & 0xff) << 8) | ((c & 0xff) << 16) | ((d & 0xff) << 24);
}

__global__ __launch_bounds__(256) void k_fused1(const float* __restrict__ x,
                                                const float* __restrict__ w,
                                                int8_t* __restrict__ xq,
                                                float* __restrict__ fact,
                                                double* __restrict__ partials) {
    int t = threadIdx.x;
    if (blockIdx.x >= 8192) {
        int b = blockIdx.x - 8192;
        const float4* w4 = (const float4*)(w + b * 4096);
        double s = 0.0;
#pragma unroll
        for (int i = 0; i < 4; ++i) {
            float4 v = w4[i * 256 + t];
            s += (double)fabsf(v.x) + (double)fabsf(v.y) +
                 (double)fabsf(v.z) + (double)fabsf(v.w);
        }
#pragma unroll
        for (int off = 32; off > 0; off >>= 1) s += __shfl_down(s, off, 64);
        __shared__ double lds[4];
        if ((t & 63) == 0) lds[t >> 6] = s;
        __syncthreads();
        if (t == 0) partials[b] = ((lds[0] + lds[1]) + (lds[2] + lds[3]));
        return;
    }
    int wid = t >> 6;
    int lane = t & 63;
    int token = blockIdx.x * 4 + wid;
    const float* xr = x + (size_t)token * 1024;
    float4 v[4];
    float m = 0.0f;
#pragma unroll
    for (int c = 0; c < 4; ++c) {
        v[c] = *(const float4*)(xr + c * 256 + lane * 4);
        m = fmaxf(m, fmaxf(fmaxf(fabsf(v[c].x), fabsf(v[c].y)),
                           fmaxf(fabsf(v[c].z), fabsf(v[c].w))));
    }
#pragma unroll
    for (int off = 32; off > 0; off >>= 1) m = fmaxf(m, __shfl_xor(m, off, 64));
    m = fmaxf(m, 1e-5f);
    float as = 127.0f / m;
    int* xqo = (int*)xq;
#pragma unroll
    for (int c = 0; c < 4; ++c)
        xqo[token * 256 + c * 64 + lane] = q8pack(v[c], as);
    if (lane == 0) fact[token] = 1.0f / as;
}

// ---------------- kernel 2: fused scale-reduce (redundant, deterministic) + wquant ----
__global__ __launch_bounds__(256) void k_fused2(const float* __restrict__ w,
                                                const double* __restrict__ partials,
                                                int8_t* __restrict__ qw,
                                                float* __restrict__ scale_f) {
    int t = threadIdx.x;
    double s = partials[t];
#pragma unroll
    for (int off = 32; off > 0; off >>= 1) s += __shfl_down(s, off, 64);
    __shared__ double lds[4];
    if ((t & 63) == 0) lds[t >> 6] = s;
    __syncthreads();
    __shared__ double sc_sh;
    if (t == 0) {
        double m = ((lds[0] + lds[1]) + (lds[2] + lds[3])) / 1048576.0;
        if (m < 1e-5) m = 1e-5;
        sc_sh = m;
        if (blockIdx.x == 0) *scale_f = (float)m;
    }
    __syncthreads();
    double half_s = 0.5 * sc_sh;

    int idx = blockIdx.x * 2048 + t * 8;
    float4 v0 = *(const float4*)(w + idx);
    float4 v1 = *(const float4*)(w + idx + 4);
    float f[8] = {v0.x, v0.y, v0.z, v0.w, v1.x, v1.y, v1.z, v1.w};
    union { char c[8]; int2 p; } u;
#pragma unroll
    for (int i = 0; i < 8; ++i) {
        char q = 0;
        if ((double)fabsf(f[i]) > half_s) q = (f[i] > 0.0f) ? 1 : -1;
        u.c[i] = q;
    }
    *(int2*)(qw + idx) = u.p;
}

// ---------------- kernel 3: r7 GEMM x2-K INSTRUMENTED (K-loop runs twice, store acc>>1) ----
// Identical structure to round-7 k_gemm5 (best passing: 89.1us total). K-loop iterates
// t=0..31 with ktile = t&15 (same data accumulated twice), continuous 3-buffer rotation
// across the wrap; epilogue stores (acc>>1) — exact. Purpose: raise the GEMM dispatch
// above the harness fill dispatches (~75us) so rocprof top-5 shows its counters.

__device__ __forceinline__ void gl_lds16(const void* g, void* l) {
    __builtin_amdgcn_global_load_lds((const __attribute__((address_space(1))) void*)g,
                                     (__attribute__((address_space(3))) void*)l, 16, 0, 0);
}

__global__ __launch_bounds__(512, 4) void k_gemm5x2(const int8_t* __restrict__ A,
                                                    const int8_t* __restrict__ B,
                                                    const float* __restrict__ fact,
                                                    const float* __restrict__ scale_f,
                                                    const float* __restrict__ bias,
                                                    float* __restrict__ out) {
    __shared__ int8_t smem[73728];          // 3 x (A 8192 | B 16384)

    const int tid  = threadIdx.x;
    const int lane = tid & 63;
    const int wid  = tid >> 6;
    const int wm   = wid >> 2;              // 0..1
    const int wn   = wid & 3;               // 0..3
    const int l31  = lane & 31;
    const int l5   = lane >> 5;

    int bid = blockIdx.x;
    int swz = (bid & 7) * 128 + (bid >> 3);
    int tm = swz >> 2;                      // 0..255
    int tn = swz & 3;                       // 0..3

    const int8_t* Ag = A + (size_t)tm * 128 * 1024;
    const int8_t* Bg = B + (size_t)tn * 256 * 1024;

    const int spr = tid >> 2;               // staging row 0..127
    const int ssl = tid & 3;                // staging slot 0..3

    auto stage = [&](int buf, int kb) {
        int base = buf * 24576;
        gl_lds16(Ag + (size_t)spr * 1024 + kb + (((ssl ^ ((spr >> 1) & 3))) << 4),
                 smem + base + tid * 16);
        gl_lds16(Bg + (size_t)spr * 1024 + kb + (((ssl ^ ((spr >> 1) & 3))) << 4),
                 smem + base + 8192 + tid * 16);
        int pr2 = 128 + spr;
        gl_lds16(Bg + (size_t)pr2 * 1024 + kb + (((ssl ^ ((pr2 >> 1) & 3))) << 4),
                 smem + base + 8192 + 8192 + tid * 16);
    };
    auto ldA = [&](int buf, int mt, int ks) -> i32x4 {
        int r = wm * 64 + mt * 32 + l31;
        int s = ((ks << 1) | l5) ^ ((r >> 1) & 3);
        return *(const i32x4*)(smem + buf * 24576 + r * 64 + (s << 4));
    };
    auto ldB = [&](int buf, int nt, int ks) -> i32x4 {
        int r = wn * 64 + nt * 32 + l31;
        int s = ((ks << 1) | l5) ^ ((r >> 1) & 3);
        return *(const i32x4*)(smem + buf * 24576 + 8192 + r * 64 + (s << 4));
    };

    i32x16 acc[2][2];
#pragma unroll
    for (int i = 0; i < 2; ++i)
#pragma unroll
        for (int j = 0; j < 2; ++j)
#pragma unroll
            for (int k = 0; k < 16; ++k) acc[i][j][k] = 0;

    // prologue: batches for (k-)tiles 0 and 1
    stage(0, 0);
    stage(1, 64);
    asm volatile("s_waitcnt vmcnt(3)" ::: "memory");
    __builtin_amdgcn_s_barrier();

    i32x4 aR[2][2], bR[2][2];

#pragma unroll
    for (int t = 0; t < 32; ++t) {          // 2 passes over K (ktile = t & 15)
        const int buf = t % 3;

#pragma unroll
        for (int mt = 0; mt < 2; ++mt)
#pragma unroll
            for (int ks = 0; ks < 2; ++ks) aR[mt][ks] = ldA(buf, mt, ks);
#pragma unroll
        for (int nt = 0; nt < 2; ++nt)
#pragma unroll
            for (int ks = 0; ks < 2; ++ks) bR[nt][ks] = ldB(buf, nt, ks);

        if (t < 30) stage((t + 2) % 3, ((t + 2) & 15) * 64);

        if (t <= 29) asm volatile("s_waitcnt vmcnt(3) lgkmcnt(0)" ::: "memory");
        else         asm volatile("s_waitcnt vmcnt(0) lgkmcnt(0)" ::: "memory");
        __builtin_amdgcn_s_barrier();

        __builtin_amdgcn_s_setprio(1);
#pragma unroll
        for (int ks = 0; ks < 2; ++ks)
#pragma unroll
            for (int mt = 0; mt < 2; ++mt)
#pragma unroll
                for (int nt = 0; nt < 2; ++nt)
                    acc[mt][nt] = __builtin_amdgcn_mfma_i32_32x32x32_i8(
                        aR[mt][ks], bR[nt][ks], acc[mt][nt], 0, 0, 0);
        __builtin_amdgcn_s_setprio(0);
    }

    // ---- epilogue: acc holds 2x the true sum; >>1 is exact ----
    const float sc = *scale_f;
#pragma unroll
    for (int mt = 0; mt < 2; ++mt) {
        int rbase = tm * 128 + wm * 64 + mt * 32 + 4 * l5;
        float fr[16];
#pragma unroll
        for (int r = 0; r < 16; ++r)
            fr[r] = sc * fact[rbase + (r & 3) + 8 * (r >> 2)];
#pragma unroll
        for (int nt = 0; nt < 2; ++nt) {
            int c = tn * 256 + wn * 64 + nt * 32 + l31;
            float bv = bias[c];
#pragma unroll
            for (int r = 0; r < 16; ++r) {
                int row = rbase + (r & 3) + 8 * (r >> 2);
                out[(size_t)row * 1024 + c] = (float)(acc[mt][nt][r] >> 1) * fr[r] + bv;
            }
        }
    }
}

extern "C" void kernel_launch(void* const* d_in, const int* in_sizes, int n_in,
                              void* d_out, int out_size, void* d_ws, size_t ws_size,
                              hipStream_t stream) {
    const float* x    = (const float*)d_in[0];
    const float* w    = (const float*)d_in[1];
    const float* bias = (const float*)d_in[2];
    float* out = (float*)d_out;
    char* ws = (char*)d_ws;

    double* partials = (double*)ws;
    float*  scale_f  = (float*)(ws + WS_SCALEF);
    float*  fact     = (float*)(ws + WS_FACT);
    int8_t* xq       = (int8_t*)(ws + WS_XQ);
    int8_t* qw       = (int8_t*)(ws + WS_QW);

    k_fused1<<<8448, 256, 0, stream>>>(x, w, xq, fact, partials);
    k_fused2<<<512, 256, 0, stream>>>(w, partials, qw, scale_f);
    k_gemm5x2<<<1024, 512, 0, stream>>>(xq, qw, fact, scale_f, bias, out);
}

// Round 14
// 90.736 us; speedup vs baseline: 1.7900x; 1.7900x over previous
//
#include <hip/hip_runtime.h>
#include <stdint.h>

using i32x4  = __attribute__((ext_vector_type(4))) int;
using i32x16 = __attribute__((ext_vector_type(16))) int;

// ---------------- ws layout ----------------
#define WS_SCALED   2048
#define WS_SCALEF   2056
#define WS_FACT     4096
#define WS_XQ       (1u << 20)
#define WS_QW       ((1u << 20) + (32u << 20))

// Tiled operand layout (both xq and qw), MFMA-fragment order:
//   chunk = 16 contiguous K bytes of one row.
//   addr  = RB*32768 + kt*2048 + (ks*64 + kh*32 + (row&31))*16
//         = RB*32768 + kt*2048 + c16*512 + (row&31)*16   with c16 = kt-local chunk id
//   (RB = row>>5, kt = k>>6, ks = (k>>5)&1, kh = (k>>4)&1)

// ---------------- kernel 1: fused aquant (tiled out) + wabs partials ----------------
__device__ inline int q8pack(float4 f, float as) {
    int a = (int)fminf(fmaxf(rintf(f.x * as), -128.0f), 127.0f);
    int b = (int)fminf(fmaxf(rintf(f.y * as), -128.0f), 127.0f);
    int c = (int)fminf(fmaxf(rintf(f.z * as), -128.0f), 127.0f);
    int d = (int)fminf(fmaxf(rintf(f.w * as), -128.0f), 127.0f);
    return (a & 0xff) | ((b & 0xff) << 8) | ((c & 0xff) << 16) | ((d & 0xff) << 24);
}

__global__ __launch_bounds__(256) void k_fused1(const float* __restrict__ x,
                                                const float* __restrict__ w,
                                                int8_t* __restrict__ xq,
                                                float* __restrict__ fact,
                                                double* __restrict__ partials) {
    int t = threadIdx.x;
    if (blockIdx.x >= 8192) {
        int b = blockIdx.x - 8192;
        const float4* w4 = (const float4*)(w + b * 4096);
        double s = 0.0;
#pragma unroll
        for (int i = 0; i < 4; ++i) {
            float4 v = w4[i * 256 + t];
            s += (double)fabsf(v.x) + (double)fabsf(v.y) +
                 (double)fabsf(v.z) + (double)fabsf(v.w);
        }
#pragma unroll
        for (int off = 32; off > 0; off >>= 1) s += __shfl_down(s, off, 64);
        __shared__ double lds[4];
        if ((t & 63) == 0) lds[t >> 6] = s;
        __syncthreads();
        if (t == 0) partials[b] = ((lds[0] + lds[1]) + (lds[2] + lds[3]));
        return;
    }
    __shared__ int8_t xbuf[4096];           // 4 rows x 64 chunks x 16B
    int wid = t >> 6;
    int lane = t & 63;
    int token = blockIdx.x * 4 + wid;
    // lane owns 16 contiguous floats: k = lane*16 .. +15  (lane == chunk id)
    const float4* xr = (const float4*)(x + (size_t)token * 1024 + lane * 16);
    float4 v0 = xr[0], v1 = xr[1], v2 = xr[2], v3 = xr[3];
    float m = fmaxf(fmaxf(fmaxf(fabsf(v0.x), fabsf(v0.y)), fmaxf(fabsf(v0.z), fabsf(v0.w))),
                    fmaxf(fmaxf(fabsf(v1.x), fabsf(v1.y)), fmaxf(fabsf(v1.z), fabsf(v1.w))));
    m = fmaxf(m, fmaxf(fmaxf(fabsf(v2.x), fabsf(v2.y)), fmaxf(fabsf(v2.z), fabsf(v2.w))));
    m = fmaxf(m, fmaxf(fmaxf(fabsf(v3.x), fabsf(v3.y)), fmaxf(fabsf(v3.z), fabsf(v3.w))));
#pragma unroll
    for (int off = 32; off > 0; off >>= 1) m = fmaxf(m, __shfl_xor(m, off, 64));
    m = fmaxf(m, 1e-5f);
    float as = 127.0f / m;
    i32x4 pk;
    pk[0] = q8pack(v0, as); pk[1] = q8pack(v1, as);
    pk[2] = q8pack(v2, as); pk[3] = q8pack(v3, as);
    *(i32x4*)(xbuf + wid * 1024 + lane * 16) = pk;
    if (lane == 0) fact[token] = 1.0f / as;
    __syncthreads();
    // repack: thread t -> row rl = t&3 of this block, chunk n = t>>2; 4-thread groups
    // write 64B contiguous to the tiled layout.
    int rl = t & 3, n = t >> 2;
    i32x4 c = *(const i32x4*)(xbuf + rl * 1024 + n * 16);
    *(i32x4*)(xq + (size_t)(blockIdx.x >> 3) * 32768 + n * 512 +
              ((blockIdx.x & 7) * 4 + rl) * 16) = c;
}

// ---------------- kernel 2: fused scale-reduce + wquant (tiled out) ----------------
__global__ __launch_bounds__(256) void k_fused2(const float* __restrict__ w,
                                                const double* __restrict__ partials,
                                                int8_t* __restrict__ qw,
                                                float* __restrict__ scale_f) {
    int t = threadIdx.x;
    double s = partials[t];
#pragma unroll
    for (int off = 32; off > 0; off >>= 1) s += __shfl_down(s, off, 64);
    __shared__ double lds[4];
    if ((t & 63) == 0) lds[t >> 6] = s;
    __syncthreads();
    __shared__ double sc_sh;
    if (t == 0) {
        double m = ((lds[0] + lds[1]) + (lds[2] + lds[3])) / 1048576.0;
        if (m < 1e-5) m = 1e-5;
        sc_sh = m;
        if (blockIdx.x == 0) *scale_f = (float)m;
    }
    __syncthreads();
    double half_s = 0.5 * sc_sh;

    // thread t: row = blk*4 + (t>>6), 16 contiguous weights at c16 = t&63
    int row = blockIdx.x * 4 + (t >> 6);
    int c16 = t & 63;
    const float4* wp = (const float4*)(w + (size_t)row * 1024 + c16 * 16);
    float4 v0 = wp[0], v1 = wp[1], v2 = wp[2], v3 = wp[3];
    float f[16] = {v0.x, v0.y, v0.z, v0.w, v1.x, v1.y, v1.z, v1.w,
                   v2.x, v2.y, v2.z, v2.w, v3.x, v3.y, v3.z, v3.w};
    union { char c[16]; i32x4 p; } u;
#pragma unroll
    for (int i = 0; i < 16; ++i) {
        char q = 0;
        if ((double)fabsf(f[i]) > half_s) q = (f[i] > 0.0f) ? 1 : -1;
        u.c[i] = q;
    }
    *(i32x4*)(qw + (size_t)(row >> 5) * 32768 + c16 * 512 + (row & 31) * 16) = u.p;
}

// ---------------- kernel 3: i8 GEMM, r7 schedule, tiled operands (0-conflict LDS) ----
// BM=128, BN=256, BK=64; 512 thr = 8 waves (2M x 4N), per-wave 64x64 (2x2 of 32x32x32).
// LDS 72KB = 3 rotating buffers x (A 8KB | B 16KB), chunk-linear (matches global tiling).
// Staging: global LINEAR runs -> LDS LINEAR (gl_lds native). ds_read_b128 lane-linear.
// Schedule identical to r7: stage(t+2) | vmcnt(3) | barrier | reads | MFMA.

__device__ __forceinline__ void gl_lds16(const void* g, void* l) {
    __builtin_amdgcn_global_load_lds((const __attribute__((address_space(1))) void*)g,
                                     (__attribute__((address_space(3))) void*)l, 16, 0, 0);
}

__global__ __launch_bounds__(512, 4) void k_gemm9(const int8_t* __restrict__ A,
                                                  const int8_t* __restrict__ B,
                                                  const float* __restrict__ fact,
                                                  const float* __restrict__ scale_f,
                                                  const float* __restrict__ bias,
                                                  float* __restrict__ out) {
    __shared__ int8_t smem[73728];          // 3 x (A 8192 | B 16384)

    const int tid  = threadIdx.x;
    const int lane = tid & 63;
    const int wid  = tid >> 6;
    const int wm   = wid >> 2;              // 0..1
    const int wn   = wid & 3;               // 0..3
    const int l31  = lane & 31;
    const int l5   = lane >> 5;

    int bid = blockIdx.x;
    int swz = (bid & 7) * 128 + (bid >> 3);
    int tm = swz >> 2;                      // 0..255
    int tn = swz & 3;                       // 0..3

    const int8_t* Atld = A + (size_t)tm * 131072;   // 4 RBs of 32KB
    const int8_t* Btld = B + (size_t)tn * 262144;   // 8 RBs of 32KB

    auto stage = [&](int buf, int kt) {
        int8_t* base = smem + buf * 24576;
        int p2 = 512 + tid;
        gl_lds16(Atld + ((tid >> 7) * 32768) + kt * 2048 + ((tid & 127) * 16),
                 base + tid * 16);
        gl_lds16(Btld + ((tid >> 7) * 32768) + kt * 2048 + ((tid & 127) * 16),
                 base + 8192 + tid * 16);
        gl_lds16(Btld + ((p2 >> 7) * 32768) + kt * 2048 + ((p2 & 127) * 16),
                 base + 8192 + p2 * 16);
    };
    auto ldA = [&](int buf, int mt, int ks) -> i32x4 {
        return *(const i32x4*)(smem + buf * 24576 + (wm * 2 + mt) * 2048 + ks * 1024 + lane * 16);
    };
    auto ldB = [&](int buf, int nt, int ks) -> i32x4 {
        return *(const i32x4*)(smem + buf * 24576 + 8192 + (wn * 2 + nt) * 2048 + ks * 1024 + lane * 16);
    };

    i32x16 acc[2][2];
#pragma unroll
    for (int i = 0; i < 2; ++i)
#pragma unroll
        for (int j = 0; j < 2; ++j)
#pragma unroll
            for (int k = 0; k < 16; ++k) acc[i][j][k] = 0;

    // prologue: K-tiles 0 and 1
    stage(0, 0);
    stage(1, 1);
    asm volatile("s_waitcnt vmcnt(3)" ::: "memory");   // my tile-0 loads landed
    __builtin_amdgcn_s_barrier();                      // all waves' tile-0 landed

    i32x4 aR[2][2], bR[2][2];

#pragma unroll
    for (int t = 0; t < 16; ++t) {
        const int buf = t % 3;

#pragma unroll
        for (int mt = 0; mt < 2; ++mt)
#pragma unroll
            for (int ks = 0; ks < 2; ++ks) aR[mt][ks] = ldA(buf, mt, ks);
#pragma unroll
        for (int nt = 0; nt < 2; ++nt)
#pragma unroll
            for (int ks = 0; ks < 2; ++ks) bR[nt][ks] = ldB(buf, nt, ks);

        if (t < 14) stage((t + 2) % 3, t + 2);

        if (t <= 13) asm volatile("s_waitcnt vmcnt(3) lgkmcnt(0)" ::: "memory");
        else         asm volatile("s_waitcnt vmcnt(0) lgkmcnt(0)" ::: "memory");
        __builtin_amdgcn_s_barrier();

        __builtin_amdgcn_s_setprio(1);
#pragma unroll
        for (int ks = 0; ks < 2; ++ks)
#pragma unroll
            for (int mt = 0; mt < 2; ++mt)
#pragma unroll
                for (int nt = 0; nt < 2; ++nt)
                    acc[mt][nt] = __builtin_amdgcn_mfma_i32_32x32x32_i8(
                        aR[mt][ks], bR[nt][ks], acc[mt][nt], 0, 0, 0);
        __builtin_amdgcn_s_setprio(0);
    }

    // ---- epilogue: direct stores ----
    const float sc = *scale_f;
#pragma unroll
    for (int mt = 0; mt < 2; ++mt) {
        int rbase = tm * 128 + wm * 64 + mt * 32 + 4 * l5;
        float fr[16];
#pragma unroll
        for (int r = 0; r < 16; ++r)
            fr[r] = sc * fact[rbase + (r & 3) + 8 * (r >> 2)];
#pragma unroll
        for (int nt = 0; nt < 2; ++nt) {
            int c = tn * 256 + wn * 64 + nt * 32 + l31;
            float bv = bias[c];
#pragma unroll
            for (int r = 0; r < 16; ++r) {
                int row = rbase + (r & 3) + 8 * (r >> 2);
                out[(size_t)row * 1024 + c] = (float)acc[mt][nt][r] * fr[r] + bv;
            }
        }
    }
}

extern "C" void kernel_launch(void* const* d_in, const int* in_sizes, int n_in,
                              void* d_out, int out_size, void* d_ws, size_t ws_size,
                              hipStream_t stream) {
    const float* x    = (const float*)d_in[0];
    const float* w    = (const float*)d_in[1];
    const float* bias = (const float*)d_in[2];
    float* out = (float*)d_out;
    char* ws = (char*)d_ws;

    double* partials = (double*)ws;
    float*  scale_f  = (float*)(ws + WS_SCALEF);
    float*  fact     = (float*)(ws + WS_FACT);
    int8_t* xq       = (int8_t*)(ws + WS_XQ);
    int8_t* qw       = (int8_t*)(ws + WS_QW);

    k_fused1<<<8448, 256, 0, stream>>>(x, w, xq, fact, partials);
    k_fused2<<<256, 256, 0, stream>>>(w, partials, qw, scale_f);
    k_gemm9<<<1024, 512, 0, stream>>>(xq, qw, fact, scale_f, bias, out);
}